// Round 8
// baseline (108.728 us; speedup 1.0000x reference)
//
#include <hip/hip_runtime.h>
#include <hip/hip_bf16.h>

#define F 64
#define R 64
#define O 64
#define BLOCK_B 64   // batch rows per block (1024 threads, 16 waves)

typedef short bf16x8 __attribute__((ext_vector_type(8)));
typedef float f32x4 __attribute__((ext_vector_type(4)));
typedef float f32x2 __attribute__((ext_vector_type(2)));

static __device__ __forceinline__ short f2bf(float f) {
    unsigned u = __builtin_bit_cast(unsigned, f);
    unsigned r = (u + 0x7fffu + ((u >> 16) & 1u)) >> 16;
    return (short)r;
}

// ---------------------------------------------------------------------------
// Prep kernel (flat, 146 blocks x 256) — proven variant.
//   threads [0, 33280): pack W (fp32) -> Wpk (bf16, MFMA B-fragment order):
//     dst bf16x8 idx = ((nt*65 + f)*2 + kk)*64 + lane
//     elem j = W[o][f*64 + r], o = nt*16+(lane&15), r = (lane>>4)*8 + j + kk*32
//   threads [33280, 37376): prm[u] = {s, mn*s, t, c}, u = f*64 + r
// ---------------------------------------------------------------------------
__global__ __launch_bounds__(256) void fq_prep(
        const float* __restrict__ tt, const float* __restrict__ mean,
        const float* __restrict__ std_, const float* __restrict__ W,
        float* __restrict__ prm, unsigned short* __restrict__ Wpk)
{
    const int tg = blockIdx.x * 256 + threadIdx.x;
    if (tg < 65 * 512) {
        const int f    = tg >> 9;
        const int u8   = tg & 511;
        const int lane = u8 & 63;
        const int kk   = (u8 >> 6) & 1;
        const int nt   = u8 >> 7;
        const int o    = nt * 16 + (lane & 15);
        const int rb   = ((lane >> 4) << 3) + kk * 32;
        const float* src = W + o * 4160 + f * 64 + rb;
        unsigned short v[8];
#pragma unroll
        for (int j = 0; j < 8; ++j) v[j] = (unsigned short)f2bf(src[j]);
        const int dst = ((nt * 65 + f) * 2 + kk) * 64 + lane;
        *(bf16x8*)(Wpk + (size_t)dst * 8) = *(bf16x8*)v;
    } else if (tg < 65 * 512 + 4096) {
        const int u = tg - 65 * 512;
        float sd = std_[u];
        float mn = mean[u];
        float th = tanhf(tt[u]);
        float s  = 1.2011224087864498f / sd;  // sqrt(log2(e)) / std
        float4 p;
        p.x = s;
        p.y = mn * s;
        p.z = th;
        p.w = 0.5f * (1.0f - th);
        ((float4*)prm)[u] = p;
    }
}

// ---------------------------------------------------------------------------
// Main fused kernel: block = 64 batch rows, 1024 threads (16 waves).
// wave w: nt = w>>2 (16 cols), g = (w>>1)&1 (rows 32g..32g+31, 2 tiles),
//         fh = w&1 (K-half: f in [32*fh, 32*fh+32), fh=1 also does bias).
// Split-K doubles resident waves (32/CU cap = 100%) at constant W traffic;
// per-wave state identical to round 7's spill-free 2-tile shape.
// fh partials merge through a 16 KB LDS epi buffer.
// ---------------------------------------------------------------------------
__global__ __launch_bounds__(1024, 4) void fq_main(
        const float* __restrict__ X,
        const float4* __restrict__ prm,
        const bf16x8* __restrict__ Wp,
        float* __restrict__ out)
{
    __shared__ __align__(16) float xt[64][68];        // [f][row]
    __shared__ __align__(16) float fire_lds[64][68];  // [row][r]
    __shared__ float rinv[BLOCK_B];
    __shared__ __align__(16) float epi[16][64][4];    // [(nt*2+g)*2+mm][lane][reg]

    const int t    = threadIdx.x;
    const int lane = t & 63;
    const int w    = __builtin_amdgcn_readfirstlane(t >> 6);  // wave 0..15
    const int b0   = blockIdx.x * BLOCK_B;

    // ---- issue X load early (held in a register through stage 1) -----------
    const int xrow = t >> 4;          // 0..63
    const int xf4  = (t & 15) * 4;
    float4 xh = *(const float4*)(X + (size_t)(b0 + xrow) * 64 + xf4);

    // ---- stage 1: firing strengths, rows 4w..4w+3, lane = r ----------------
    {
        f32x2 fire2[2] = {(f32x2){1.f, 1.f}, (f32x2){1.f, 1.f}};
        const float* Xw = X + (size_t)(b0 + 4 * w) * 64;
        float4 p = prm[lane];          // f = 0
#pragma unroll 2
        for (int f = 0; f < F; ++f) {
            const int pf = (f + 1 < 64) ? f + 1 : 63;
            float4 pn = prm[pf * 64 + lane];      // distance-1 prefetch
            f32x2 t2 = (f32x2){p.z, p.z};
            f32x2 c2 = (f32x2){p.w, p.w};
#pragma unroll
            for (int i = 0; i < 2; ++i) {
                float x0 = Xw[(2 * i) * 64 + f];      // wave-uniform -> s_load
                float x1 = Xw[(2 * i + 1) * 64 + f];
                f32x2 z;
                z.x = __builtin_fmaf(x0, p.x, -p.y);
                z.y = __builtin_fmaf(x1, p.x, -p.y);
                f32x2 nz = -(z * z);
                f32x2 g2;
                g2.x = __builtin_amdgcn_exp2f(nz.x);
                g2.y = __builtin_amdgcn_exp2f(nz.y);
                fire2[i] *= g2 * t2 + c2;
            }
            p = pn;
        }
        // write X slab (transposed) and fire rows, then one barrier
        xt[xf4 + 0][xrow] = xh.x;
        xt[xf4 + 1][xrow] = xh.y;
        xt[xf4 + 2][xrow] = xh.z;
        xt[xf4 + 3][xrow] = xh.w;
        const int r0 = 4 * w;
        fire_lds[r0 + 0][lane] = fire2[0].x;
        fire_lds[r0 + 1][lane] = fire2[0].y;
        fire_lds[r0 + 2][lane] = fire2[1].x;
        fire_lds[r0 + 3][lane] = fire2[1].y;
    }
    __syncthreads();

    // ---- row sums: 16 threads per row, shuffle-reduce ----------------------
    {
        const int row = t >> 4;
        const int c4  = (t & 15) * 4;
        f32x4 s4 = *(const f32x4*)&fire_lds[row][c4];
        float s = (s4[0] + s4[1]) + (s4[2] + s4[3]);
        s += __shfl_xor(s, 1);
        s += __shfl_xor(s, 2);
        s += __shfl_xor(s, 4);
        s += __shfl_xor(s, 8);
        if ((t & 15) == 0) rinv[row] = 1.0f / s;
    }
    __syncthreads();

    // ---- stage 2: split-K GEMM, 2 row-tiles per wave -----------------------
    const int m_in = lane & 15;
    const int quad = lane >> 4;
    const int nt   = w >> 2;
    const int g    = (w >> 1) & 1;
    const int fh   = w & 1;
    const int q8   = quad * 8;

    bf16x8 wfrag[2][2];   // [mm][kk], rows 32g + 16mm + m_in
#pragma unroll
    for (int mm = 0; mm < 2; ++mm) {
        const int myrow = 32 * g + 16 * mm + m_in;
        const float rs  = rinv[myrow];
#pragma unroll
        for (int kk = 0; kk < 2; ++kk) {
            f32x4 a = *(const f32x4*)&fire_lds[myrow][q8 + kk * 32];
            f32x4 b = *(const f32x4*)&fire_lds[myrow][q8 + kk * 32 + 4];
            wfrag[mm][kk][0] = f2bf(a[0] * rs); wfrag[mm][kk][1] = f2bf(a[1] * rs);
            wfrag[mm][kk][2] = f2bf(a[2] * rs); wfrag[mm][kk][3] = f2bf(a[3] * rs);
            wfrag[mm][kk][4] = f2bf(b[0] * rs); wfrag[mm][kk][5] = f2bf(b[1] * rs);
            wfrag[mm][kk][6] = f2bf(b[2] * rs); wfrag[mm][kk][7] = f2bf(b[3] * rs);
        }
    }

    const bf16x8* wpb = Wp + (size_t)(nt * 130) * 64 + lane;
    const int f0 = fh * 32;

    f32x4 acc[2];
    acc[0] = (f32x4){0.f, 0.f, 0.f, 0.f};
    acc[1] = (f32x4){0.f, 0.f, 0.f, 0.f};
    const f32x4 z4 = (f32x4){0.f, 0.f, 0.f, 0.f};

    // distance-1 register prefetch; clamp targets the bias slab (64), so for
    // fh=1 the exit prefetch IS the bias fragment pair.
    bf16x8 p0 = wpb[(2 * f0) * 64];
    bf16x8 p1 = wpb[(2 * f0 + 1) * 64];
#pragma unroll 2
    for (int i = 0; i < 32; ++i) {
        const int f = f0 + i;
        bf16x8 c0 = p0, c1 = p1;
        const int sp = (f + 1 < 64) ? f + 1 : 64;
        p0 = wpb[(2 * sp) * 64];
        p1 = wpb[(2 * sp + 1) * 64];
#pragma unroll
        for (int mm = 0; mm < 2; ++mm) {
            f32x4 U = __builtin_amdgcn_mfma_f32_16x16x32_bf16(wfrag[mm][0], c0, z4, 0, 0, 0);
            U = __builtin_amdgcn_mfma_f32_16x16x32_bf16(wfrag[mm][1], c1, U, 0, 0, 0);
            f32x4 xv = *(const f32x4*)&xt[f][32 * g + 16 * mm + quad * 4];
#pragma unroll
            for (int reg = 0; reg < 4; ++reg)
                acc[mm][reg] = __builtin_fmaf(xv[reg], U[reg], acc[mm][reg]);
        }
    }

    if (fh == 1) {
        // bias slab (x = 1): pair resident in p0/p1 from the exit prefetch
#pragma unroll
        for (int mm = 0; mm < 2; ++mm) {
            f32x4 U = __builtin_amdgcn_mfma_f32_16x16x32_bf16(wfrag[mm][0], p0, z4, 0, 0, 0);
            U = __builtin_amdgcn_mfma_f32_16x16x32_bf16(wfrag[mm][1], p1, U, 0, 0, 0);
#pragma unroll
            for (int reg = 0; reg < 4; ++reg)
                acc[mm][reg] += U[reg];
        }
#pragma unroll
        for (int mm = 0; mm < 2; ++mm)
            *(f32x4*)&epi[(nt * 2 + g) * 2 + mm][lane][0] = acc[mm];
    }
    __syncthreads();

    if (fh == 0) {
#pragma unroll
        for (int mm = 0; mm < 2; ++mm) {
            f32x4 r = acc[mm] + *(const f32x4*)&epi[(nt * 2 + g) * 2 + mm][lane][0];
#pragma unroll
            for (int reg = 0; reg < 4; ++reg) {
                const int row = b0 + 32 * g + 16 * mm + quad * 4 + reg;
                out[(size_t)row * 64 + nt * 16 + m_in] = r[reg];
            }
        }
    }
}

extern "C" void kernel_launch(void* const* d_in, const int* in_sizes, int n_in,
                              void* d_out, int out_size, void* d_ws, size_t ws_size,
                              hipStream_t stream) {
    const float* X    = (const float*)d_in[0];
    const float* tt   = (const float*)d_in[1];
    const float* mean = (const float*)d_in[2];
    const float* std_ = (const float*)d_in[3];
    const float* W    = (const float*)d_in[4];
    float* out = (float*)d_out;

    // workspace: prm (float4 x 4096 = 64 KiB) | Wpk (bf16 x 65*512*8 = 520 KiB)
    float* prm = (float*)d_ws;
    unsigned short* Wpk = (unsigned short*)((char*)d_ws + 65536);

    fq_prep<<<146, 256, 0, stream>>>(tt, mean, std_, W, prm, Wpk);

    const int nblocks = 32768 / BLOCK_B;  // 512 blocks x 1024 thr = 8192 waves
    fq_main<<<nblocks, 1024, 0, stream>>>(X, (const float4*)prm,
                                          (const bf16x8*)Wpk, out);
}

// Round 9
// 103.134 us; speedup vs baseline: 1.0542x; 1.0542x over previous
//
#include <hip/hip_runtime.h>
#include <hip/hip_bf16.h>

#define F 64
#define R 64
#define O 64
#define BLOCK_B 64   // batch rows per block (512 threads, 8 waves)

typedef short bf16x8 __attribute__((ext_vector_type(8)));
typedef float f32x4 __attribute__((ext_vector_type(4)));
typedef float f32x2 __attribute__((ext_vector_type(2)));

static __device__ __forceinline__ unsigned short f2bf(float f) {
    unsigned u = __builtin_bit_cast(unsigned, f);
    unsigned r = (u + 0x7fffu + ((u >> 16) & 1u)) >> 16;
    return (unsigned short)r;
}

// ---------------------------------------------------------------------------
// Prep kernel (flat, 146 blocks x 256) — proven variant.
//   threads [0, 33280): pack W (fp32) -> Wpk (bf16, MFMA B-fragment order):
//     dst bf16x8 idx = ((nt*65 + f)*2 + kk)*64 + lane
//     elem j = W[o][f*64 + r], o = nt*16+(lane&15), r = (lane>>4)*8 + j + kk*32
//   threads [33280, 37376): prm[u] = {s, mn*s, t, c}, u = f*64 + r
// ---------------------------------------------------------------------------
__global__ __launch_bounds__(256) void fq_prep(
        const float* __restrict__ tt, const float* __restrict__ mean,
        const float* __restrict__ std_, const float* __restrict__ W,
        float* __restrict__ prm, unsigned short* __restrict__ Wpk)
{
    const int tg = blockIdx.x * 256 + threadIdx.x;
    if (tg < 65 * 512) {
        const int f    = tg >> 9;
        const int u8   = tg & 511;
        const int lane = u8 & 63;
        const int kk   = (u8 >> 6) & 1;
        const int nt   = u8 >> 7;
        const int o    = nt * 16 + (lane & 15);
        const int rb   = ((lane >> 4) << 3) + kk * 32;
        const float* src = W + o * 4160 + f * 64 + rb;
        unsigned short v[8];
#pragma unroll
        for (int j = 0; j < 8; ++j) v[j] = f2bf(src[j]);
        const int dst = ((nt * 65 + f) * 2 + kk) * 64 + lane;
        *(bf16x8*)(Wpk + (size_t)dst * 8) = *(bf16x8*)v;
    } else if (tg < 65 * 512 + 4096) {
        const int u = tg - 65 * 512;
        float sd = std_[u];
        float mn = mean[u];
        float th = tanhf(tt[u]);
        float s  = 1.2011224087864498f / sd;  // sqrt(log2(e)) / std
        float4 p;
        p.x = s;
        p.y = mn * s;
        p.z = th;
        p.w = 0.5f * (1.0f - th);
        ((float4*)prm)[u] = p;
    }
}

// ---------------------------------------------------------------------------
// Main fused kernel: block = 64 batch rows, 512 threads (8 waves).
// Normalization DEFERRED to epilogue (out linear in w) — so:
//   stage 1 writes raw fire as bf16 in A-frag-readable layout + in-wave
//   butterfly row-sums -> rinv. ONE barrier total.
//   stage 2: wfrag = direct ds_read_b128 of fire bf16; r7 GEMM loop
//   (dist-2 even/odd W prefetch, issued before stage 1); epilogue *= rinv.
// ---------------------------------------------------------------------------
__global__ __launch_bounds__(512, 2) void fq_main(
        const float* __restrict__ X,
        const float4* __restrict__ prm,
        const bf16x8* __restrict__ Wp,
        float* __restrict__ out)
{
    __shared__ __align__(16) float xt[64][68];              // [f][row]
    __shared__ __align__(16) unsigned short fireb[64][72];  // [row][r] bf16
    __shared__ __align__(16) float rinv[BLOCK_B];

    const int t    = threadIdx.x;
    const int lane = t & 63;
    const int w    = __builtin_amdgcn_readfirstlane(t >> 6);  // wave 0..7
    const int b0   = blockIdx.x * BLOCK_B;
    const int nt   = w >> 1;
    const int g    = w & 1;

    // ---- issue X loads + first W prefetch pair early (in flight thru st.1) -
    const int xrow = t >> 4;          // 0..31
    const int xf4  = (t & 15) * 4;
    float4 xh0 = *(const float4*)(X + (size_t)(b0 + xrow) * 64 + xf4);
    float4 xh1 = *(const float4*)(X + (size_t)(b0 + xrow + 32) * 64 + xf4);

    const bf16x8* wpb = Wp + (size_t)(nt * 130) * 64 + lane;
    bf16x8 pe0 = wpb[0 * 64],  pe1 = wpb[1 * 64];     // f = 0
    bf16x8 po0 = wpb[2 * 64],  po1 = wpb[3 * 64];     // f = 1

    // ---- stage 1: firing strengths, rows 8w..8w+7, lane = r ----------------
    {
        f32x2 fire2[4];
#pragma unroll
        for (int i = 0; i < 4; ++i) fire2[i] = (f32x2){1.f, 1.f};
        const float* Xw = X + (size_t)(b0 + 8 * w) * 64;
        float4 p = prm[lane];          // f = 0
#pragma unroll 2
        for (int f = 0; f < F; ++f) {
            const int pf = (f + 1 < 64) ? f + 1 : 63;
            float4 pn = prm[pf * 64 + lane];      // distance-1 prefetch
            f32x2 t2 = (f32x2){p.z, p.z};
            f32x2 c2 = (f32x2){p.w, p.w};
#pragma unroll
            for (int i = 0; i < 4; ++i) {
                float x0 = Xw[(2 * i) * 64 + f];      // wave-uniform -> s_load
                float x1 = Xw[(2 * i + 1) * 64 + f];
                f32x2 z;
                z.x = __builtin_fmaf(x0, p.x, -p.y);
                z.y = __builtin_fmaf(x1, p.x, -p.y);
                f32x2 nz = -(z * z);
                f32x2 g2;
                g2.x = __builtin_amdgcn_exp2f(nz.x);
                g2.y = __builtin_amdgcn_exp2f(nz.y);
                fire2[i] *= g2 * t2 + c2;
            }
            p = pn;
        }
        // write X slab (transposed) + raw-fire bf16 rows
        xt[xf4 + 0][xrow] = xh0.x;  xt[xf4 + 0][xrow + 32] = xh1.x;
        xt[xf4 + 1][xrow] = xh0.y;  xt[xf4 + 1][xrow + 32] = xh1.y;
        xt[xf4 + 2][xrow] = xh0.z;  xt[xf4 + 2][xrow + 32] = xh1.z;
        xt[xf4 + 3][xrow] = xh0.w;  xt[xf4 + 3][xrow + 32] = xh1.w;
        const int r0 = 8 * w;
#pragma unroll
        for (int i = 0; i < 4; ++i) {
            fireb[r0 + 2 * i][lane]     = f2bf(fire2[i].x);
            fireb[r0 + 2 * i + 1][lane] = f2bf(fire2[i].y);
        }
        // in-wave butterfly row sums -> rinv (no extra barrier/phase)
#pragma unroll
        for (int i = 0; i < 4; ++i) {
            float sx = fire2[i].x, sy = fire2[i].y;
#pragma unroll
            for (int d = 1; d < 64; d <<= 1) {
                sx += __shfl_xor(sx, d);
                sy += __shfl_xor(sy, d);
            }
            if (lane == 0) {
                rinv[r0 + 2 * i]     = 1.0f / sx;
                rinv[r0 + 2 * i + 1] = 1.0f / sy;
            }
        }
    }
    __syncthreads();   // the ONE barrier

    // ---- stage 2: 2 row-tiles per wave, dist-2 W prefetch ------------------
    const int m_in = lane & 15;
    const int quad = lane >> 4;
    const int q16  = quad * 16;   // byte offset of quad's 8-bf16 chunk

    bf16x8 wfrag[2][2];   // [mm][kk] — direct reads, raw (unnormalized) fire
#pragma unroll
    for (int mm = 0; mm < 2; ++mm) {
        const int myrow = 32 * g + 16 * mm + m_in;
        wfrag[mm][0] = *(const bf16x8*)((const char*)&fireb[myrow][0] + q16);
        wfrag[mm][1] = *(const bf16x8*)((const char*)&fireb[myrow][32] + q16);
    }

    f32x4 acc[2];
    acc[0] = (f32x4){0.f, 0.f, 0.f, 0.f};
    acc[1] = (f32x4){0.f, 0.f, 0.f, 0.f};
    const f32x4 z4 = (f32x4){0.f, 0.f, 0.f, 0.f};

#pragma unroll 2
    for (int i = 0; i < 32; ++i) {
        const int fe = 2 * i, fo = 2 * i + 1;
        bf16x8 ce0 = pe0, ce1 = pe1, co0 = po0, co1 = po1;
        const int se = (fe + 2 <= 64) ? fe + 2 : 64;   // clamp to bias slab
        const int so = (fo + 2 <= 64) ? fo + 2 : 64;
        pe0 = wpb[(2 * se) * 64];  pe1 = wpb[(2 * se + 1) * 64];
        po0 = wpb[(2 * so) * 64];  po1 = wpb[(2 * so + 1) * 64];
#pragma unroll
        for (int mm = 0; mm < 2; ++mm) {
            f32x4 U = __builtin_amdgcn_mfma_f32_16x16x32_bf16(wfrag[mm][0], ce0, z4, 0, 0, 0);
            U = __builtin_amdgcn_mfma_f32_16x16x32_bf16(wfrag[mm][1], ce1, U, 0, 0, 0);
            f32x4 xv = *(const f32x4*)&xt[fe][32 * g + 16 * mm + quad * 4];
#pragma unroll
            for (int reg = 0; reg < 4; ++reg)
                acc[mm][reg] = __builtin_fmaf(xv[reg], U[reg], acc[mm][reg]);
        }
#pragma unroll
        for (int mm = 0; mm < 2; ++mm) {
            f32x4 U = __builtin_amdgcn_mfma_f32_16x16x32_bf16(wfrag[mm][0], co0, z4, 0, 0, 0);
            U = __builtin_amdgcn_mfma_f32_16x16x32_bf16(wfrag[mm][1], co1, U, 0, 0, 0);
            f32x4 xv = *(const f32x4*)&xt[fo][32 * g + 16 * mm + quad * 4];
#pragma unroll
            for (int reg = 0; reg < 4; ++reg)
                acc[mm][reg] = __builtin_fmaf(xv[reg], U[reg], acc[mm][reg]);
        }
    }

    // bias slab (x = 1): pair resident in pe0/pe1 from the exit prefetch
#pragma unroll
    for (int mm = 0; mm < 2; ++mm) {
        f32x4 U = __builtin_amdgcn_mfma_f32_16x16x32_bf16(wfrag[mm][0], pe0, z4, 0, 0, 0);
        U = __builtin_amdgcn_mfma_f32_16x16x32_bf16(wfrag[mm][1], pe1, U, 0, 0, 0);
#pragma unroll
        for (int reg = 0; reg < 4; ++reg)
            acc[mm][reg] += U[reg];
    }

    // epilogue: out = acc * rinv[row];  C/D: col = lane&15, row = quad*4+reg
#pragma unroll
    for (int mm = 0; mm < 2; ++mm) {
        f32x4 rv = *(const f32x4*)&rinv[32 * g + 16 * mm + quad * 4];
#pragma unroll
        for (int reg = 0; reg < 4; ++reg) {
            const int row = b0 + 32 * g + 16 * mm + quad * 4 + reg;
            out[(size_t)row * 64 + nt * 16 + m_in] = acc[mm][reg] * rv[reg];
        }
    }
}

extern "C" void kernel_launch(void* const* d_in, const int* in_sizes, int n_in,
                              void* d_out, int out_size, void* d_ws, size_t ws_size,
                              hipStream_t stream) {
    const float* X    = (const float*)d_in[0];
    const float* tt   = (const float*)d_in[1];
    const float* mean = (const float*)d_in[2];
    const float* std_ = (const float*)d_in[3];
    const float* W    = (const float*)d_in[4];
    float* out = (float*)d_out;

    // workspace: prm (float4 x 4096 = 64 KiB) | Wpk (bf16 x 65*512*8 = 520 KiB)
    float* prm = (float*)d_ws;
    unsigned short* Wpk = (unsigned short*)((char*)d_ws + 65536);

    fq_prep<<<146, 256, 0, stream>>>(tt, mean, std_, W, prm, Wpk);

    const int nblocks = 32768 / BLOCK_B;  // 512 blocks x 512 thr = 4096 waves
    fq_main<<<nblocks, 512, 0, stream>>>(X, (const float4*)prm,
                                         (const bf16x8*)Wpk, out);
}